// Round 6
// baseline (93.122 us; speedup 1.0000x reference)
//
#include <hip/hip_runtime.h>

// RandomHingeFern: B=4096, C_in=512, O=1024, D=10, L=2^10=1024
// out[b,o] = weights[o, leaf(b,o)] * min_d |x[b, ord[o,d]] - thr[o,d]|
//
// Two kernels:
//  1) transpose x [B][CIN] -> xT [CIN][B] in d_ws (8 MB, written fully each call)
//  2) fern: lane<->b, o wave-uniform. x access = xT[ord][b0+lane] : one
//     coalesced 256B L2-hit load per (o,d). ord/thr via scalar loads.
//     Output transposed through a 16KB swizzled LDS tile -> occupancy 8 blocks/CU.

#define B_TOT  4096
#define CIN    512
#define O_TOT  1024
#define DEPTH  10
#define LEAVES 1024

typedef float vf4 __attribute__((ext_vector_type(4)));

// ---------------- Kernel 1: x -> xT (64x64 tiles via swizzled LDS) ----------
__global__ __launch_bounds__(256, 4) void transpose_kernel(
    const float* __restrict__ x,   // [B][CIN]
    float* __restrict__ xT)        // [CIN][B]
{
    __shared__ float tile[64 * 64];         // 16 KB, slot = r*64 + (c ^ r)
    const int t  = threadIdx.x;
    const int c0 = blockIdx.x * 64;         // channel tile (8)
    const int r0 = blockIdx.y * 64;         // batch tile  (64)

#pragma unroll
    for (int k = 0; k < 4; ++k) {
        const int id = k * 256 + t;         // 0..1023
        const int r  = id >> 4;             // 0..63
        const int c4 = id & 15;             // float4 col group
        const vf4 v = *reinterpret_cast<const vf4*>(
            x + (size_t)(r0 + r) * CIN + c0 + (c4 << 2));
        const int c = c4 << 2;
        tile[r * 64 + ((c + 0) ^ r)] = v.x;
        tile[r * 64 + ((c + 1) ^ r)] = v.y;
        tile[r * 64 + ((c + 2) ^ r)] = v.z;
        tile[r * 64 + ((c + 3) ^ r)] = v.w;
    }
    __syncthreads();

#pragma unroll
    for (int k = 0; k < 4; ++k) {
        const int id = k * 256 + t;
        const int c  = id >> 4;             // channel row of xT
        const int j4 = id & 15;             // b float4 group
        vf4 v;
        v.x = tile[(j4 * 4 + 0) * 64 + (c ^ (j4 * 4 + 0))];
        v.y = tile[(j4 * 4 + 1) * 64 + (c ^ (j4 * 4 + 1))];
        v.z = tile[(j4 * 4 + 2) * 64 + (c ^ (j4 * 4 + 2))];
        v.w = tile[(j4 * 4 + 3) * 64 + (c ^ (j4 * 4 + 3))];
        *reinterpret_cast<vf4*>(xT + (size_t)(c0 + c) * B_TOT + r0 + (j4 << 2)) = v;
    }
}

// ---------------- Kernel 2: fern ----------------
// block: 256 threads (4 waves). b-tile 64 (lane<->b), o-tile 64 (16 o per wave).
__global__ __launch_bounds__(256, 4) void fern_kernel(
    const float* __restrict__ xT,         // [CIN][B]
    const float* __restrict__ thresholds, // [O][DEPTH]
    const int*   __restrict__ ordinals,   // [O][DEPTH]
    const float* __restrict__ weights,    // [O][LEAVES]
    float*       __restrict__ out)        // [B][O]
{
    __shared__ float osh[64 * 64];        // 16 KB, osh[b*64 + (o ^ b)]

    const int t    = threadIdx.x;
    const int lane = t & 63;                                   // b_local
    const int wu   = __builtin_amdgcn_readfirstlane(t >> 6);   // wave 0..3
    const int b0   = blockIdx.x * 64;
    const int o0   = blockIdx.y * 64;

#pragma unroll 2
    for (int i = 0; i < 16; ++i) {
        const int ol = wu * 16 + i;                 // uniform
        const int o  = o0 + ol;
        const int*   op = ordinals   + o * DEPTH;   // SGPR base -> s_load
        const float* tp = thresholds + o * DEPTH;   // SGPR base -> s_load

        int   leaf = 0;
        float mm   = 1e30f;
#pragma unroll
        for (int d = 0; d < DEPTH; ++d) {
            const int   ord = op[d];                // scalar
            const float xv  = xT[(size_t)ord * B_TOT + b0 + lane]; // coalesced 256B
            const float mg  = xv - tp[d];
            leaf = (leaf << 1) | (mg > 0.0f ? 1 : 0);
            mm   = fminf(mm, fabsf(mg));
        }
        const float wv = weights[(size_t)o * LEAVES + leaf];   // same-row gather
        osh[lane * 64 + (ol ^ lane)] = wv * mm;
    }
    __syncthreads();

    // Flush 64x64 tile: coalesced nontemporal float4.
#pragma unroll
    for (int k = 0; k < 4; ++k) {
        const int id = k * 256 + t;
        const int rb = id >> 4;             // b row
        const int ob = (id & 15) << 2;      // o col of .x
        vf4 v;
        v.x = osh[rb * 64 + ((ob + 0) ^ rb)];
        v.y = osh[rb * 64 + ((ob + 1) ^ rb)];
        v.z = osh[rb * 64 + ((ob + 2) ^ rb)];
        v.w = osh[rb * 64 + ((ob + 3) ^ rb)];
        __builtin_nontemporal_store(v, reinterpret_cast<vf4*>(
            out + (size_t)(b0 + rb) * O_TOT + o0 + ob));
    }
}

extern "C" void kernel_launch(void* const* d_in, const int* in_sizes, int n_in,
                              void* d_out, int out_size, void* d_ws, size_t ws_size,
                              hipStream_t stream) {
    const float* x          = (const float*)d_in[0];
    const float* thresholds = (const float*)d_in[1];
    const int*   ordinals   = (const int*)d_in[2];
    const float* weights    = (const float*)d_in[3];
    float*       out        = (float*)d_out;
    float*       xT         = (float*)d_ws;     // 8 MB

    dim3 tg(CIN / 64, B_TOT / 64);              // 8 x 64 = 512 blocks
    transpose_kernel<<<tg, 256, 0, stream>>>(x, xT);

    dim3 fg(B_TOT / 64, O_TOT / 64);            // 64 x 16 = 1024 blocks
    fern_kernel<<<fg, 256, 0, stream>>>(xT, thresholds, ordinals, weights, out);
}

// Round 7
// 87.397 us; speedup vs baseline: 1.0655x; 1.0655x over previous
//
#include <hip/hip_runtime.h>

// RandomHingeFern: B=4096, C_in=512, O=1024, D=10, L=2^10=1024
// out[b,o] = weights[o, leaf(b,o)] * min_d |x[b, ord[o,d]] - thr[o,d]|
//
// Kernel 1: transpose x [B][CIN] -> xT [CIN][B] (d_ws, 8 MB).
// Kernel 2: fern. lane<->b (float2 pair: b = b0+2*lane, +1), o wave-uniform.
//   x access: one coalesced 512B float2 load per (o,d) pair of outputs (L2-hit).
//   ord/thr: wave-uniform scalar loads. weights: same-row gather.
//   out: o-major float2 LDS tile (XOR swizzle), nontemporal float4 flush.

#define B_TOT  4096
#define CIN    512
#define O_TOT  1024
#define DEPTH  10
#define LEAVES 1024
#define BT     128
#define OTILE  16

typedef float vf4 __attribute__((ext_vector_type(4)));
typedef float vf2 __attribute__((ext_vector_type(2)));

// ---------------- Kernel 1: x -> xT (64x64 tiles via swizzled LDS) ----------
__global__ __launch_bounds__(256, 4) void transpose_kernel(
    const float* __restrict__ x,   // [B][CIN]
    float* __restrict__ xT)        // [CIN][B]
{
    __shared__ float tile[64 * 64];         // 16 KB, slot = r*64 + (c ^ r)
    const int t  = threadIdx.x;
    const int c0 = blockIdx.x * 64;         // channel tile (8)
    const int r0 = blockIdx.y * 64;         // batch tile  (64)

#pragma unroll
    for (int k = 0; k < 4; ++k) {
        const int id = k * 256 + t;         // 0..1023
        const int r  = id >> 4;             // 0..63
        const int c4 = id & 15;             // float4 col group
        const vf4 v = *reinterpret_cast<const vf4*>(
            x + (size_t)(r0 + r) * CIN + c0 + (c4 << 2));
        const int c = c4 << 2;
        tile[r * 64 + ((c + 0) ^ r)] = v.x;
        tile[r * 64 + ((c + 1) ^ r)] = v.y;
        tile[r * 64 + ((c + 2) ^ r)] = v.z;
        tile[r * 64 + ((c + 3) ^ r)] = v.w;
    }
    __syncthreads();

#pragma unroll
    for (int k = 0; k < 4; ++k) {
        const int id = k * 256 + t;
        const int c  = id >> 4;             // channel row of xT
        const int j4 = id & 15;             // b float4 group
        vf4 v;
        v.x = tile[(j4 * 4 + 0) * 64 + (c ^ (j4 * 4 + 0))];
        v.y = tile[(j4 * 4 + 1) * 64 + (c ^ (j4 * 4 + 1))];
        v.z = tile[(j4 * 4 + 2) * 64 + (c ^ (j4 * 4 + 2))];
        v.w = tile[(j4 * 4 + 3) * 64 + (c ^ (j4 * 4 + 3))];
        *reinterpret_cast<vf4*>(xT + (size_t)(c0 + c) * B_TOT + r0 + (j4 << 2)) = v;
    }
}

// ---------------- Kernel 2: fern ----------------
// block: 256 threads (4 waves). b-tile 128 (float2/lane), o-tile 16 (4/wave).
__global__ __launch_bounds__(256, 4) void fern_kernel(
    const float* __restrict__ xT,         // [CIN][B]
    const float* __restrict__ thresholds, // [O][DEPTH]
    const int*   __restrict__ ordinals,   // [O][DEPTH]
    const float* __restrict__ weights,    // [O][LEAVES]
    float*       __restrict__ out)        // [B][O]
{
    __shared__ vf2 osh[OTILE * 64];       // 8 KB, [ol][bp ^ ol]

    const int t    = threadIdx.x;
    const int lane = t & 63;                                   // b-pair index
    const int wu   = __builtin_amdgcn_readfirstlane(t >> 6);   // wave 0..3
    const int b0   = blockIdx.x * BT;
    const int o0   = blockIdx.y * OTILE;

#pragma unroll
    for (int i = 0; i < 4; ++i) {
        const int ol = wu * 4 + i;                  // wave-uniform
        const int o  = o0 + ol;
        const int*   op = ordinals   + o * DEPTH;   // SGPR base -> s_load
        const float* tp = thresholds + o * DEPTH;   // SGPR base -> s_load

        // Issue all 10 coalesced 512B loads up front (deep MLP window).
        vf2 xv[DEPTH];
#pragma unroll
        for (int d = 0; d < DEPTH; ++d)
            xv[d] = *reinterpret_cast<const vf2*>(
                xT + (size_t)op[d] * B_TOT + b0 + 2 * lane);

        int   leaf0 = 0, leaf1 = 0;
        float mm0 = 1e30f, mm1 = 1e30f;
#pragma unroll
        for (int d = 0; d < DEPTH; ++d) {
            const float thr = tp[d];
            const float g0  = xv[d].x - thr;
            const float g1  = xv[d].y - thr;
            leaf0 = (leaf0 << 1) | (g0 > 0.0f ? 1 : 0);
            leaf1 = (leaf1 << 1) | (g1 > 0.0f ? 1 : 0);
            mm0   = fminf(mm0, fabsf(g0));
            mm1   = fminf(mm1, fabsf(g1));
        }
        const float* wrow = weights + (size_t)o * LEAVES;
        vf2 r;
        r.x = wrow[leaf0] * mm0;                    // same-row gathers
        r.y = wrow[leaf1] * mm1;
        osh[ol * 64 + (lane ^ ol)] = r;             // conflict-free b64 write
    }
    __syncthreads();

    // Flush: 128 b-rows x 16 o = 512 float4; 2 per thread; 64B-coalesced NT.
    const float* oshf = reinterpret_cast<const float*>(osh);
#pragma unroll
    for (int k = 0; k < 2; ++k) {
        const int id = k * 256 + t;
        const int r  = id >> 2;             // b row 0..127
        const int q  = (id & 3) << 2;       // o col of .x
        vf4 v;
        v.x = oshf[((q + 0) * 64 + ((r >> 1) ^ (q + 0))) * 2 + (r & 1)];
        v.y = oshf[((q + 1) * 64 + ((r >> 1) ^ (q + 1))) * 2 + (r & 1)];
        v.z = oshf[((q + 2) * 64 + ((r >> 1) ^ (q + 2))) * 2 + (r & 1)];
        v.w = oshf[((q + 3) * 64 + ((r >> 1) ^ (q + 3))) * 2 + (r & 1)];
        __builtin_nontemporal_store(v, reinterpret_cast<vf4*>(
            out + (size_t)(b0 + r) * O_TOT + o0 + q));
    }
}

extern "C" void kernel_launch(void* const* d_in, const int* in_sizes, int n_in,
                              void* d_out, int out_size, void* d_ws, size_t ws_size,
                              hipStream_t stream) {
    const float* x          = (const float*)d_in[0];
    const float* thresholds = (const float*)d_in[1];
    const int*   ordinals   = (const int*)d_in[2];
    const float* weights    = (const float*)d_in[3];
    float*       out        = (float*)d_out;
    float*       xT         = (float*)d_ws;     // 8 MB

    dim3 tg(CIN / 64, B_TOT / 64);              // 8 x 64 = 512 blocks
    transpose_kernel<<<tg, 256, 0, stream>>>(x, xT);

    dim3 fg(B_TOT / BT, O_TOT / OTILE);         // 32 x 64 = 2048 blocks
    fern_kernel<<<fg, 256, 0, stream>>>(xT, thresholds, ordinals, weights, out);
}